// Round 1
// baseline (387.455 us; speedup 1.0000x reference)
//
#include <hip/hip_runtime.h>
#include <math.h>

#define NB 64
#define NT 512
#define ND 768
#define NK 29
#define WPAD 772
#define EPAD 68
#define L2E 1.4426950408889634f
#define LN2 0.6931471805599453f
#define NEG_BIG -1e30f

// ---------------------------------------------------------------------------
// Kernel 1: emissions  em[tok][k] = dot(emb[x[tok]], w[k]) + b[k]
// grid = 1024 blocks x 256 threads. Block handles one k-half (15 or 14 rows,
// staged in LDS once). Each wave handles 16 tokens: e rows staged per-wave
// into LDS in 64-float chunks, software-pipelined (next chunk's global loads
// issued before computing current chunk).
// ---------------------------------------------------------------------------
__global__ __launch_bounds__(256) void k_emissions(
    const int* __restrict__ x, const float* __restrict__ emb,
    const float* __restrict__ w, const float* __restrict__ bias,
    float* __restrict__ em)
{
    __shared__ __align__(16) float wlds[15 * WPAD];     // 46320 B
    __shared__ __align__(16) float elds[4 * 16 * EPAD]; // 17408 B

    const int half = blockIdx.x & 1;
    const int kbase = half * 15;
    const int cnt = 15 - half;          // 15 or 14 rows

    // stage w-half into LDS (block-wide, once)
    for (int idx = threadIdx.x; idx < cnt * ND; idx += 256) {
        int r = idx / ND;
        int d = idx - r * ND;
        wlds[r * WPAD + d] = w[(kbase + r) * ND + d];
    }
    __syncthreads();

    const int lane = threadIdx.x & 63;
    const int wv = threadIdx.x >> 6;
    const int tg = (blockIdx.x >> 1) * 4 + wv;      // 0..2047
    const long tokbase = (long)tg * 16;

    const int kl = lane & 15;
    const int kc = kl < cnt ? kl : cnt - 1;
    const int g = lane >> 4;                        // 0..3 (token group; also staging row group)
    const int off = (lane & 15) * 4;                // float offset within 64-float chunk

    // staging source rows: lane stages tokens (g + 4*i), i=0..3
    const float* srow0 = emb + (long)x[tokbase + g + 0] * ND + off;
    const float* srow1 = emb + (long)x[tokbase + g + 4] * ND + off;
    const float* srow2 = emb + (long)x[tokbase + g + 8] * ND + off;
    const float* srow3 = emb + (long)x[tokbase + g + 12] * ND + off;

    float* eb = elds + wv * (16 * EPAD);
    const float* wrow = wlds + kc * WPAD;
    const float* erow = eb + (g * 4) * EPAD;        // compute-tokens g*4 + j

    float4 r0 = *(const float4*)(srow0);
    float4 r1 = *(const float4*)(srow1);
    float4 r2 = *(const float4*)(srow2);
    float4 r3 = *(const float4*)(srow3);

    float acc0 = 0.f, acc1 = 0.f, acc2 = 0.f, acc3 = 0.f;

    for (int c = 0; c < 12; ++c) {
        // write staged chunk to LDS (same-wave DS ordering makes this safe)
        *(float4*)(eb + (g + 0) * EPAD + off) = r0;
        *(float4*)(eb + (g + 4) * EPAD + off) = r1;
        *(float4*)(eb + (g + 8) * EPAD + off) = r2;
        *(float4*)(eb + (g + 12) * EPAD + off) = r3;
        if (c < 11) {   // issue next chunk's loads; latency hidden by compute
            r0 = *(const float4*)(srow0 + (c + 1) * 64);
            r1 = *(const float4*)(srow1 + (c + 1) * 64);
            r2 = *(const float4*)(srow2 + (c + 1) * 64);
            r3 = *(const float4*)(srow3 + (c + 1) * 64);
        }
        const float* wc = wrow + c * 64;
#pragma unroll
        for (int dd = 0; dd < 64; dd += 4) {
            float4 w4 = *(const float4*)(wc + dd);
            float4 e0 = *(const float4*)(erow + 0 * EPAD + dd);
            float4 e1 = *(const float4*)(erow + 1 * EPAD + dd);
            float4 e2 = *(const float4*)(erow + 2 * EPAD + dd);
            float4 e3 = *(const float4*)(erow + 3 * EPAD + dd);
            acc0 += e0.x * w4.x + e0.y * w4.y + e0.z * w4.z + e0.w * w4.w;
            acc1 += e1.x * w4.x + e1.y * w4.y + e1.z * w4.z + e1.w * w4.w;
            acc2 += e2.x * w4.x + e2.y * w4.y + e2.z * w4.z + e2.w * w4.w;
            acc3 += e3.x * w4.x + e3.y * w4.y + e3.z * w4.z + e3.w * w4.w;
        }
    }

    if (kl < cnt) {
        float bb = bias[kbase + kl];
        long t0 = tokbase + g * 4;
        em[(t0 + 0) * NK + kbase + kl] = acc0 + bb;
        em[(t0 + 1) * NK + kbase + kl] = acc1 + bb;
        em[(t0 + 2) * NK + kbase + kl] = acc2 + bb;
        em[(t0 + 3) * NK + kbase + kl] = acc3 + bb;
    }
}

// ---------------------------------------------------------------------------
// Kernel 2: scans. blocks 0..63 = CRF forward (logZ - num per batch),
// blocks 64..127 = Viterbi + backtrace (writes decoded). 64 threads = 1 wave.
// Lane layout: j = lane&31 (state, j<29 active), h = lane>>5 (i-range half).
// ---------------------------------------------------------------------------
__global__ __launch_bounds__(64) void k_scan(
    const float* __restrict__ em, const int* __restrict__ tags,
    const float* __restrict__ st, const float* __restrict__ en,
    const float* __restrict__ tr, float* __restrict__ part,
    float* __restrict__ out)
{
    __shared__ __align__(16) float sA[32];
    __shared__ unsigned char sbp[511 * 32];
    __shared__ unsigned char spath[512];

    const int lane = threadIdx.x;
    const int j = lane & 31;
    const int h = lane >> 5;
    const bool jact = (j < NK);
    const int jc = jact ? j : NK - 1;

    if (blockIdx.x < NB) {
        // ----------------- CRF forward (logsumexp scan) -----------------
        const int b = blockIdx.x;
        const float* emb_b = em + (size_t)b * NT * NK;
        float Ecol[16];
#pragma unroll
        for (int ii = 0; ii < 16; ++ii) {
            int i = h * 16 + ii;
            Ecol[ii] = (i < NK) ? expf(tr[i * NK + jc]) : 0.0f;
        }
        float alpha = jact ? (st[jc] + emb_b[jc]) : NEG_BIG;
        float em1 = emb_b[1 * NK + jc];
        float em2 = emb_b[2 * NK + jc];

        for (int t = 1; t < NT; ++t) {
            float emt = em1;
            em1 = em2;
            if (t + 2 < NT) em2 = emb_b[(t + 2) * NK + jc];

            float M = alpha;
#pragma unroll
            for (int s = 32; s; s >>= 1) M = fmaxf(M, __shfl_xor(M, s));
            float A = exp2f((alpha - M) * L2E);     // inactive lanes -> 0
            if (h == 0) sA[j] = A;
            __syncthreads();
            float4 a0 = *(const float4*)&sA[h * 16 + 0];
            float4 a1 = *(const float4*)&sA[h * 16 + 4];
            float4 a2 = *(const float4*)&sA[h * 16 + 8];
            float4 a3 = *(const float4*)&sA[h * 16 + 12];
            float s0 = a0.x * Ecol[0] + a0.y * Ecol[1] + a0.z * Ecol[2] + a0.w * Ecol[3]
                     + a1.x * Ecol[4] + a1.y * Ecol[5] + a1.z * Ecol[6] + a1.w * Ecol[7]
                     + a2.x * Ecol[8] + a2.y * Ecol[9] + a2.z * Ecol[10] + a2.w * Ecol[11]
                     + a3.x * Ecol[12] + a3.y * Ecol[13] + a3.z * Ecol[14] + a3.w * Ecol[15];
            s0 += __shfl_xor(s0, 32);
            float na = emt + M + log2f(s0) * LN2;
            alpha = jact ? na : NEG_BIG;
            __syncthreads();   // protect sA before next write
        }
        // logZ = logsumexp(alpha + end)
        float v = jact ? (alpha + en[jc]) : NEG_BIG;
        float M = v;
#pragma unroll
        for (int s = 32; s; s >>= 1) M = fmaxf(M, __shfl_xor(M, s));
        float e = (jact && h == 0) ? exp2f((v - M) * L2E) : 0.0f;
#pragma unroll
        for (int s = 32; s; s >>= 1) e += __shfl_xor(e, s);
        float logZ = M + log2f(e) * LN2;
        // numerator
        const int* tg = tags + b * NT;
        float p = 0.0f;
        for (int t = lane; t < NT; t += 64) {
            int tt = tg[t];
            p += emb_b[t * NK + tt];
            if (t == 0) p += st[tt];
            else        p += tr[tg[t - 1] * NK + tt];
            if (t == NT - 1) p += en[tt];
        }
#pragma unroll
        for (int s = 32; s; s >>= 1) p += __shfl_xor(p, s);
        if (lane == 0) part[b] = logZ - p;
    } else {
        // ----------------- Viterbi + backtrace -----------------
        const int b = blockIdx.x - NB;
        const float* emb_b = em + (size_t)b * NT * NK;
        float Tcol[16];
#pragma unroll
        for (int ii = 0; ii < 16; ++ii) {
            int i = h * 16 + ii;
            Tcol[ii] = (i < NK) ? tr[i * NK + jc] : 0.0f;
        }
        float sc = jact ? (st[jc] + emb_b[jc]) : NEG_BIG;
        float em1 = emb_b[1 * NK + jc];
        float em2 = emb_b[2 * NK + jc];

        for (int t = 1; t < NT; ++t) {
            float emt = em1;
            em1 = em2;
            if (t + 2 < NT) em2 = emb_b[(t + 2) * NK + jc];

            if (h == 0) sA[j] = sc;
            __syncthreads();
            float4 a0 = *(const float4*)&sA[h * 16 + 0];
            float4 a1 = *(const float4*)&sA[h * 16 + 4];
            float4 a2 = *(const float4*)&sA[h * 16 + 8];
            float4 a3 = *(const float4*)&sA[h * 16 + 12];
            float sv[16] = { a0.x, a0.y, a0.z, a0.w, a1.x, a1.y, a1.z, a1.w,
                             a2.x, a2.y, a2.z, a2.w, a3.x, a3.y, a3.z, a3.w };
            float best = -3e38f; int bi = 0;
#pragma unroll
            for (int ii = 0; ii < 16; ++ii) {
                float vv = sv[ii] + Tcol[ii];
                if (vv > best) { best = vv; bi = h * 16 + ii; }
            }
            float ob = __shfl_xor(best, 32);
            int   oi = __shfl_xor(bi, 32);
            float bl = h ? ob : best; int il = h ? oi : bi;   // low-i half result
            float bh = h ? best : ob; int ih = h ? bi : oi;   // high-i half result
            float fb = (bh > bl) ? bh : bl;                   // strict: ties -> lower i
            int   fi = (bh > bl) ? ih : il;
            if (h == 0) sbp[(t - 1) * 32 + j] = (unsigned char)fi;
            sc = jact ? (fb + emt) : NEG_BIG;
            __syncthreads();
        }
        float v = jact ? (sc + en[jc]) : NEG_BIG;
        float M = v;
#pragma unroll
        for (int s = 32; s; s >>= 1) M = fmaxf(M, __shfl_xor(M, s));
        unsigned long long mk = __ballot(jact && h == 0 && v == M);
        int last = (int)__builtin_ctzll(mk);      // lane index == j for h==0
        if (lane == 0) {
            int cur = last;
            spath[NT - 1] = (unsigned char)cur;
            for (int t = NT - 1; t >= 1; --t) {
                cur = sbp[(t - 1) * 32 + cur];
                spath[t - 1] = (unsigned char)cur;
            }
        }
        __syncthreads();
        float* op = out + 1 + (size_t)b * NT;
        for (int t = lane; t < NT; t += 64) op[t] = (float)spath[t];
    }
}

// ---------------------------------------------------------------------------
// Kernel 3: nll = sum_b (logZ_b - num_b)
// ---------------------------------------------------------------------------
__global__ __launch_bounds__(64) void k_finish(const float* __restrict__ part,
                                               float* __restrict__ out)
{
    float v = part[threadIdx.x];
#pragma unroll
    for (int s = 32; s; s >>= 1) v += __shfl_xor(v, s);
    if (threadIdx.x == 0) out[0] = v;
}

extern "C" void kernel_launch(void* const* d_in, const int* in_sizes, int n_in,
                              void* d_out, int out_size, void* d_ws, size_t ws_size,
                              hipStream_t stream) {
    const int*   x    = (const int*)d_in[0];
    const int*   tags = (const int*)d_in[1];
    const float* emb  = (const float*)d_in[2];
    const float* w    = (const float*)d_in[3];
    const float* bias = (const float*)d_in[4];
    const float* st   = (const float*)d_in[5];
    const float* en   = (const float*)d_in[6];
    const float* tr   = (const float*)d_in[7];
    float* out = (float*)d_out;

    float* em   = (float*)d_ws;                                   // B*T*K floats
    float* part = (float*)((char*)d_ws + (size_t)NB * NT * NK * 4); // B floats

    k_emissions<<<1024, 256, 0, stream>>>(x, emb, w, bias, em);
    k_scan<<<2 * NB, 64, 0, stream>>>(em, tags, st, en, tr, part, out);
    k_finish<<<1, 64, 0, stream>>>(part, out);
}